// Round 13
// baseline (3015.965 us; speedup 1.0000x reference)
//
#include <hip/hip_runtime.h>
#include <math.h>

#define BB   16
#define NN   32768
#define GG   128
#define KK   64
#define EDD  384
#define NT1  1024
#define PPT  32   // NN / NT1 (k_grp phases)
#define SB   8    // k_fps blocks per batch
#define SP   (NN / SB)   // 4096 points per k_fps block
#define JP   (SP / NT1)  // 4 points/thread

// ---- workspace layout (float offsets) ----
#define WS_GC     0          // [16][2][3]      = 96     (c0, cm per batch)
#define WS_F2     6240       // [32][256][64]   = 524288
#define WS_FG     530528     // [32][256]       = 8192
#define WS_F4     538720     // [32][512][64]   = 1048576
#define WS_SYNC   1587296    // u64 [2 parity][16 batch][8 blk] = 2 KB

// ---- k_grp LDS layout (float offsets past dkey[NN]) ----
#define GOFF_WSUM  (NN)        // uint [2][16] parity-buffered wave sums
#define GOFF_CNT   (NN + 32)   // int [8]: [0]=sel_cnt [1]=eq_cnt
#define GOFF_SEL   (NN + 40)   // int [64]
#define GOFF_EQB   (NN + 104)  // int [512]
#define GOFF_XL    (NN + 616)  // float [KK*3]
#define GRP_LDS_FLOATS (NN + 808)

__device__ __forceinline__ float sq3(float a, float b, float c) {
  // matches np: ((a*a + b*b) + c*c), no FMA contraction
  return __fadd_rn(__fadd_rn(__fmul_rn(a, a), __fmul_rn(b, b)), __fmul_rn(c, c));
}
__device__ __forceinline__ float dot3(float ax, float ay, float az,
                                      float bx, float by, float bz) {
  return __fadd_rn(__fadd_rn(__fmul_rn(ax, bx), __fmul_rn(ay, by)), __fmul_rn(az, bz));
}
__device__ __forceinline__ unsigned long long shfl_xor_u64(unsigned long long v,
                                                           int off) {
  unsigned lo = (unsigned)v, hi = (unsigned)(v >> 32);
  lo = __shfl_xor(lo, off);
  hi = __shfl_xor(hi, off);
  return ((unsigned long long)hi << 32) | lo;
}
// L1-bypass, L2-HIT 8-byte load (sc0 only). Agent-scope stores are
// write-through: they update the publisher's XCD-local L2 en route to the
// coherence point, so a same-XCD reader sees them at L2 latency. NOT
// guaranteed visible cross-XCD (L2s not coherent) -- callers must
// periodically escalate to a true agent-scope load for progress.
__device__ __forceinline__ unsigned long long load_u64_sc0(
    const unsigned long long* p) {
  unsigned long long v;
  asm volatile("global_load_dwordx2 %0, %1, off sc0\n\ts_waitcnt vmcnt(0)"
               : "=v"(v) : "v"(p) : "memory");
  return v;
}

// ---------------------------------------------------------------------------
// Kernel 1: FPS. R12's proven structure (SB=8, intra-block reduce -> ONE
// agent publish per block -> lanes<8 of wave0 spin -> LDS winp -> barrier B)
// with R13's hybrid spin: poll with sc0-only loads (L2-hit when the co-XCD
// swizzle holds: publisher's write-through store updated the shared local
// L2, ~250cy instead of the ~900cy MALL trip of a full agent load); every
// 256th poll escalates to a true agent-scope load so progress is guaranteed
// even if blocks land on different XCDs (G16: correctness must not depend
// on placement -- only speed does). Deadlock-free: 128 blocks <= 256 CUs
// @ ~51KB LDS => all co-resident; escalation bounds staleness.
// u64-max keeps np.argmax first-max tie rule (0xFFFF-idx low bits).
// Parity safety: round it+2's slot write happens only after this block read
// all round it+1 slots, which required every block's round-it read.
// ---------------------------------------------------------------------------
__global__ void __launch_bounds__(NT1) k_fps(const float* __restrict__ points,
                                             float* __restrict__ out,
                                             float* __restrict__ ws) {
  __shared__ float2 xyS[SP];                 // 32 KB
  __shared__ float  zS[SP];                  // 16 KB
  __shared__ float cent[GG * 3];
  __shared__ float darr[GG];
  __shared__ int msh[1];
  __shared__ unsigned long long redp[16];
  __shared__ unsigned long long winp;

  const int gb   = blockIdx.x;
  // co-XCD mapping: c = gb&7 (XCD class), blk = (gb>>3)&7, b = c*2+(gb>>6).
  const int b    = (gb & 7) * 2 + (gb >> 6);
  const int blk  = (gb >> 3) & 7;
  const int t    = threadIdx.x;
  const int wave = t >> 6, lane = t & 63;
  const float* P = points + (size_t)b * NN * 3;
  const int base = blk * SP;
  unsigned long long* slots = (unsigned long long*)(ws + WS_SYNC);

  // stage slice coords (thread-owned slots) + init reg-resident dist
#pragma unroll
  for (int j = 0; j < JP; ++j) {
    int q = t + j * NT1;
    const float* pp = P + (size_t)(base + q) * 3;
    xyS[q] = make_float2(pp[0], pp[1]);
    zS[q]  = pp[2];
  }
  float dist[JP];
#pragma unroll
  for (int j = 0; j < JP; ++j) dist[j] = INFINITY;

  float cx = P[0], cy = P[1], cz = P[2];  // centroid 0 = point 0
  if (blk == 0 && t == 0) { cent[0] = cx; cent[1] = cy; cent[2] = cz; }
  __syncthreads();

  for (int it = 1; it < GG; ++it) {
    float bd = -INFINITY; int bj = 0;
#pragma unroll
    for (int j = 0; j < JP; ++j) {
      int q = t + j * NT1;
      float2 xy = xyS[q];
      float  zz = zS[q];
      float dx = __fsub_rn(xy.x, cx);
      float dy = __fsub_rn(xy.y, cy);
      float dz = __fsub_rn(zz, cz);
      float d  = __fadd_rn(__fadd_rn(__fmul_rn(dx, dx), __fmul_rn(dy, dy)),
                           __fmul_rn(dz, dz));
      float nd = fminf(dist[j], d);
      dist[j] = nd;
      if (nd > bd) { bd = nd; bj = j; }  // ascending q + strict > => first-max
    }
    // pack: [d_bits(32) | it(16) | 0xFFFF - idx(16)]; u64 max = (max d,
    // tie min idx) = np.argmax first-max rule. idx = base+t+bj*1024 < 32768.
    unsigned long long bp =
        ((unsigned long long)__float_as_uint(bd) << 32) |
        ((unsigned)it << 16) |
        (unsigned)(0xFFFF - (base + t + (bj << 10)));
#pragma unroll
    for (int off = 1; off < 64; off <<= 1) {
      unsigned long long o = shfl_xor_u64(bp, off);
      if (o > bp) bp = o;
    }
    if (lane == 0) redp[wave] = bp;
    __syncthreads();  // barrier A
    if (wave == 0) {
      unsigned long long v = redp[lane & 15];
#pragma unroll
      for (int off = 1; off < 16; off <<= 1) {
        unsigned long long o = shfl_xor_u64(v, off);
        if (o > v) v = o;
      }
      unsigned long long* sl = slots + ((size_t)(it & 1) * 16 + b) * SB;
      if (lane == 0)
        __hip_atomic_store(&sl[blk], v, __ATOMIC_RELAXED,
                           __HIP_MEMORY_SCOPE_AGENT);
      if (lane < SB) {
        // hybrid spin: sc0 polls (local-L2 hit when co-XCD), periodic
        // agent-scope escalation for guaranteed cross-XCD progress
        unsigned long long o;
        int spins = 0;
        do {
          if ((++spins & 255) == 0)
            o = __hip_atomic_load(&sl[lane], __ATOMIC_RELAXED,
                                  __HIP_MEMORY_SCOPE_AGENT);
          else
            o = load_u64_sc0(&sl[lane]);
        } while ((unsigned)((o >> 16) & 0xFFFF) != (unsigned)it);  // tag-spin
        unsigned long long o1 = shfl_xor_u64(o, 1);
        if (o1 > o) o = o1;
        unsigned long long o2 = shfl_xor_u64(o, 2);
        if (o2 > o) o = o2;
        unsigned long long o4 = shfl_xor_u64(o, 4);
        if (o4 > o) o = o4;
        if (lane == 0) winp = o;
      }
    }
    __syncthreads();  // barrier B
    unsigned long long w = winp;
    int sv = 0xFFFF - (int)(w & 0xFFFF);
    const float* wp = P + (size_t)sv * 3;  // wave-uniform -> broadcast load
    cx = wp[0]; cy = wp[1]; cz = wp[2];
    if (blk == 0 && t == 0) {
      cent[it * 3 + 0] = cx; cent[it * 3 + 1] = cy; cent[it * 3 + 2] = cz;
    }
  }

  if (blk != 0) return;  // epilogue on block 0 of each batch only
  __syncthreads();

  // morton step 1: m = argmin_{j>=1} cdist(c0, cj), ref expansion formula
  if (t < GG) {
    float c0x = cent[0], c0y = cent[1], c0z = cent[2];
    float cjx = cent[t * 3 + 0], cjy = cent[t * 3 + 1], cjz = cent[t * 3 + 2];
    float sa = sq3(c0x, c0y, c0z);
    float sb = sq3(cjx, cjy, cjz);
    float dt = dot3(c0x, c0y, c0z, cjx, cjy, cjz);
    float dd = __fsub_rn(__fadd_rn(sa, sb), __fmul_rn(2.0f, dt));
    darr[t] = (t == 0) ? INFINITY : dd;
  }
  __syncthreads();
  if (t == 0) {
    float vd = darr[1]; int vi = 1;
    for (int j = 2; j < GG; ++j) {
      float od = darr[j];
      if (od < vd) { vd = od; vi = j; }  // strict < => first-min
    }
    msh[0] = vi;
    float* gc = ws + WS_GC + b * 6;
    gc[0] = cent[0];          gc[1] = cent[1];          gc[2] = cent[2];
    gc[3] = cent[vi * 3 + 0]; gc[4] = cent[vi * 3 + 1]; gc[5] = cent[vi * 3 + 2];
  }
  __syncthreads();
  int m = msh[0];
  // centroid output: pos0 = c0, pos1 = cm, pos>=2 = c0 (morton degeneracy)
  if (t < GG * 3) {
    int pos = t / 3, c = t % 3;
    float v = (pos == 1) ? cent[m * 3 + c] : cent[c];
    out[(size_t)b * GG * 3 + t] = v;
  }
}

// ---------------------------------------------------------------------------
// Kernel 2 (fused topk + encA): R9's binary-search selection (unchanged).
// Set-exact vs lax.top_k ((d,idx) lexicographic); encoder is k-permutation-
// invariant so set equality => identical output.
// ---------------------------------------------------------------------------
__global__ void __launch_bounds__(NT1) k_grp(
    const float* __restrict__ points, float* __restrict__ ws,
    const float* __restrict__ w1, const float* __restrict__ b1,
    const float* __restrict__ g1, const float* __restrict__ be1,
    const float* __restrict__ m1, const float* __restrict__ v1,
    const float* __restrict__ w2, const float* __restrict__ b2) {
  extern __shared__ float smem[];
  unsigned* dkey = (unsigned*)smem;          // [NN] keys; f1s overlays later
  float* f1s  = smem;                        // [128*65] = 8320 <= NN
  unsigned* wsum = (unsigned*)(smem + GOFF_WSUM);  // [2][16]
  int*   cnts = (int*)(smem + GOFF_CNT);     // [0]=sel_cnt [1]=eq_cnt
  int*   sel  = (int*)(smem + GOFF_SEL);     // [64]
  int*   eqb  = (int*)(smem + GOFF_EQB);     // [512]
  float* xl   = smem + GOFF_XL;              // [KK*3]

  const int g = blockIdx.x;
  const int b = g >> 1, which = g & 1;
  const int t = threadIdx.x;
  const int wave = t >> 6, lane = t & 63;
  const float* P = points + (size_t)b * NN * 3;
  const float* gc = ws + WS_GC + b * 6 + which * 3;
  const float cx = gc[0], cy = gc[1], cz = gc[2];
  const float sa = sq3(cx, cy, cz);

  // ---- phase 1: distances -> monotone uint keys in LDS ----
#pragma unroll
  for (int j = 0; j < PPT; ++j) {
    int p = t + j * NT1;
    const float* pp = P + (size_t)p * 3;
    float px = pp[0], py = pp[1], pz = pp[2];
    float sb = sq3(px, py, pz);
    float dt = dot3(cx, cy, cz, px, py, pz);
    float d  = __fsub_rn(__fadd_rn(sa, sb), __fmul_rn(2.0f, dt));
    unsigned u = __float_as_uint(d);
    dkey[p] = u ^ ((u & 0x80000000u) ? 0xFFFFFFFFu : 0x80000000u);
  }
  if (t < 2) cnts[t] = 0;
  __syncthreads();

  // ---- phase 2: binary search for K = min key with count(<=K) >= 64 ----
  unsigned klo = 0u, khi = 0xFFFFFFFFu;
  int par = 0;
  while (klo < khi) {  // uniform across block: 32 iterations
    unsigned mid = klo + ((khi - klo) >> 1);
    int c = 0;
#pragma unroll
    for (int j = 0; j < PPT; ++j) c += (dkey[t + j * NT1] <= mid) ? 1 : 0;
#pragma unroll
    for (int off = 1; off < 64; off <<= 1) c += __shfl_xor(c, off);
    if (lane == 0) wsum[par * 16 + wave] = (unsigned)c;
    __syncthreads();  // one barrier/iter; parity buffer kills WAR race
    int tot = 0;
#pragma unroll
    for (int w = 0; w < 16; ++w) tot += (int)wsum[par * 16 + w];
    if (tot >= KK) khi = mid; else klo = mid + 1;
    par ^= 1;
  }
  const unsigned K64 = klo;

  // count(< K64) — uniform C_lt
  {
    int c = 0;
#pragma unroll
    for (int j = 0; j < PPT; ++j) c += (dkey[t + j * NT1] < K64) ? 1 : 0;
#pragma unroll
    for (int off = 1; off < 64; off <<= 1) c += __shfl_xor(c, off);
    if (lane == 0) wsum[par * 16 + wave] = (unsigned)c;
    __syncthreads();
  }
  int C_lt = 0;
#pragma unroll
  for (int w = 0; w < 16; ++w) C_lt += (int)wsum[par * 16 + w];

  // ---- phase 3: collection (set-exact; order within sel arbitrary) ----
#pragma unroll
  for (int j = 0; j < PPT; ++j) {
    int p = t + j * NT1;
    unsigned kk = dkey[p];
    if (kk < K64) {
      int pos = atomicAdd(&cnts[0], 1);
      sel[pos] = p;
    } else if (kk == K64) {
      int pos = atomicAdd(&cnts[1], 1);
      if (pos < 512) eqb[pos] = p;
    }
  }
  __syncthreads();

  // ties: take (KK - C_lt) smallest INDICES among key==K64 (top_k rule)
  if (wave == 0) {
    int M = cnts[1]; if (M > 512) M = 512;
    int R = KK - C_lt;  // >=1 by minimality of K64
    int e[8];
#pragma unroll
    for (int q = 0; q < 8; ++q) {
      int ix = lane + q * 64;
      e[q] = (ix < M) ? eqb[ix] : 0x7FFFFFFF;
    }
    for (int r = 0; r < R; ++r) {
      int gm = e[0];
#pragma unroll
      for (int q = 1; q < 8; ++q) gm = min(gm, e[q]);
#pragma unroll
      for (int off = 1; off < 64; off <<= 1) gm = min(gm, __shfl_xor(gm, off));
      if (lane == 0) sel[C_lt + r] = gm;
#pragma unroll
      for (int q = 0; q < 8; ++q) if (e[q] == gm) e[q] = 0x7FFFFFFF;
    }
  }
  __syncthreads();

  if (t < KK) {  // local coords of the 64 selected into LDS
    int p = sel[t];
    const float* pp = P + (size_t)p * 3;
    xl[t * 3 + 0] = __fsub_rn(pp[0], cx);
    xl[t * 3 + 1] = __fsub_rn(pp[1], cy);
    xl[t * 3 + 2] = __fsub_rn(pp[2], cz);
  }
  __syncthreads();  // dkey dead after this point; f1s overlays it

  // ---- phase 4: f1 = relu(bn1(w1@x + b1)) -> f1s[128][65] ----
  {
    const int o = t & 127, kh = t >> 7;  // kh in [0,8)
    float wx = w1[o * 3 + 0], wy = w1[o * 3 + 1], wz = w1[o * 3 + 2];
    float inv = g1[o] * (1.0f / sqrtf(v1[o] + 1e-5f));
    float add = be1[o] - m1[o] * inv;
    float bb = b1[o];
#pragma unroll
    for (int kk = 0; kk < 8; ++kk) {
      int k = kh * 8 + kk;
      float f = fmaf(wx, xl[k * 3 + 0],
                fmaf(wy, xl[k * 3 + 1],
                fmaf(wz, xl[k * 3 + 2], bb)));
      f = fmaf(f, inv, add);
      f1s[o * 65 + k] = fmaxf(f, 0.0f);
    }
  }
  __syncthreads();

  // ---- phase 5: f2 = w2@f1 + b2 -> global; fg = max_k -> global ----
  const int k  = t & 63;
  const int og = __builtin_amdgcn_readfirstlane(t >> 6);  // wave-uniform [0,16)
  const int o0 = og * 16;
  float acc[16];
#pragma unroll
  for (int oo = 0; oo < 16; ++oo) acc[oo] = b2[o0 + oo];
  for (int i = 0; i < 128; ++i) {
    float xv = f1s[i * 65 + k];
#pragma unroll
    for (int oo = 0; oo < 16; ++oo)
      acc[oo] = fmaf(w2[(o0 + oo) * 128 + i], xv, acc[oo]);  // uniform -> s_load
  }
  float* f2g = ws + WS_F2 + (size_t)g * 256 * 64;
  float* fgg = ws + WS_FG + g * 256;
#pragma unroll
  for (int oo = 0; oo < 16; ++oo) f2g[(o0 + oo) * 64 + k] = acc[oo];
#pragma unroll
  for (int oo = 0; oo < 16; ++oo) {
    float v = acc[oo];
#pragma unroll
    for (int off = 1; off < 64; off <<= 1) v = fmaxf(v, __shfl_xor(v, off));
    if (k == 0) fgg[o0 + oo] = v;
  }
}

// ---------------------------------------------------------------------------
// Kernel 3 (stage B): f4 = relu(bn2(w3 @ concat([fg bcast, f2]) + b3))
// grid = 32 groups x 16 o-chunks of 32. (unchanged)
// ---------------------------------------------------------------------------
__global__ void __launch_bounds__(256) k_encB(
    float* __restrict__ ws,
    const float* __restrict__ w3, const float* __restrict__ b3,
    const float* __restrict__ g2, const float* __restrict__ be2,
    const float* __restrict__ m2, const float* __restrict__ v2) {
  __shared__ float part[32][8];
  __shared__ float sfg[32];
  const int blk = blockIdx.x;
  const int g = blk >> 4, oc = blk & 15;
  const int t = threadIdx.x;
  const int k = t & 63;
  const int og = __builtin_amdgcn_readfirstlane(t >> 6);  // [0,4)
  const int ob = oc * 32;
  const float* fgg = ws + WS_FG + g * 256;
  {
    int o = t >> 3, ih = t & 7;
    float s = 0.0f;
    int i0 = ih * 32;
    for (int ii = 0; ii < 32; ++ii) {
      int i = i0 + ii;
      s = fmaf(w3[(size_t)(ob + o) * 512 + i], fgg[i], s);
    }
    part[o][ih] = s;
  }
  __syncthreads();
  if (t < 32) {
    float s = ((part[t][0] + part[t][1]) + (part[t][2] + part[t][3])) +
              ((part[t][4] + part[t][5]) + (part[t][6] + part[t][7]));
    sfg[t] = b3[ob + t] + s;
  }
  __syncthreads();
  const int o0 = ob + og * 8;
  float acc[8];
#pragma unroll
  for (int oo = 0; oo < 8; ++oo) acc[oo] = sfg[og * 8 + oo];
  const float* f2g = ws + WS_F2 + (size_t)g * 256 * 64;
#pragma unroll 4
  for (int i = 0; i < 256; ++i) {
    float xv = f2g[i * 64 + k];
#pragma unroll
    for (int oo = 0; oo < 8; ++oo)
      acc[oo] = fmaf(w3[(size_t)(o0 + oo) * 512 + 256 + i], xv, acc[oo]);
  }
  float* f4g = ws + WS_F4 + (size_t)g * 512 * 64;
#pragma unroll
  for (int oo = 0; oo < 8; ++oo) {
    int o = o0 + oo;
    float inv = g2[o] * (1.0f / sqrtf(v2[o] + 1e-5f));
    float add = be2[o] - m2[o] * inv;
    f4g[o * 64 + k] = fmaxf(fmaf(acc[oo], inv, add), 0.0f);
  }
}

// ---------------------------------------------------------------------------
// Kernel 4 (fused stage C + broadcast): token = max_k (w4 @ f4 + b4).
// grid = 32 x 24 chunks of 16. (unchanged)
// ---------------------------------------------------------------------------
__global__ void __launch_bounds__(256) k_encCb(float* __restrict__ ws,
                                               const float* __restrict__ w4,
                                               const float* __restrict__ b4,
                                               float* __restrict__ out) {
  const int blk = blockIdx.x;
  const int g = blk / 24, oc = blk % 24;
  const int b = g >> 1, which = g & 1;
  const int t = threadIdx.x;
  const int k = t & 63;
  const int og = __builtin_amdgcn_readfirstlane(t >> 6);
  const int o0 = oc * 16 + og * 4;
  float acc[4];
#pragma unroll
  for (int oo = 0; oo < 4; ++oo) acc[oo] = b4[o0 + oo];
  const float* f4g = ws + WS_F4 + (size_t)g * 512 * 64;
#pragma unroll 8
  for (int i = 0; i < 512; ++i) {
    float xv = f4g[i * 64 + k];
#pragma unroll
    for (int oo = 0; oo < 4; ++oo)
      acc[oo] = fmaf(w4[(size_t)(o0 + oo) * 512 + i], xv, acc[oo]);
  }
#pragma unroll
  for (int oo = 0; oo < 4; ++oo) {
#pragma unroll
    for (int off = 1; off < 64; off <<= 1)
      acc[oo] = fmaxf(acc[oo], __shfl_xor(acc[oo], off));
  }
  float* tok = out + (size_t)BB * GG * 3;
  if (which == 1) {
    if (k == 0) {
      float* dst = tok + ((size_t)b * GG + 1) * EDD + o0;
#pragma unroll
      for (int oo = 0; oo < 4; ++oo) dst[oo] = acc[oo];
    }
  } else {
#pragma unroll
    for (int rep = 0; rep < 2; ++rep) {
      int pos = k + rep * 64;
      if (pos == 1) continue;
      float* dst = tok + ((size_t)b * GG + pos) * EDD + o0;
#pragma unroll
      for (int oo = 0; oo < 4; ++oo) dst[oo] = acc[oo];
    }
  }
}

extern "C" void kernel_launch(void* const* d_in, const int* in_sizes, int n_in,
                              void* d_out, int out_size, void* d_ws, size_t ws_size,
                              hipStream_t stream) {
  const float* points = (const float*)d_in[0];
  const float* w1  = (const float*)d_in[1];
  const float* b1  = (const float*)d_in[2];
  const float* g1  = (const float*)d_in[3];
  const float* be1 = (const float*)d_in[4];
  const float* m1  = (const float*)d_in[5];
  const float* v1  = (const float*)d_in[6];
  const float* w2  = (const float*)d_in[7];
  const float* b2  = (const float*)d_in[8];
  const float* w3  = (const float*)d_in[9];
  const float* b3  = (const float*)d_in[10];
  const float* g2  = (const float*)d_in[11];
  const float* be2 = (const float*)d_in[12];
  const float* m2  = (const float*)d_in[13];
  const float* v2  = (const float*)d_in[14];
  const float* w4  = (const float*)d_in[15];
  const float* b4  = (const float*)d_in[16];
  float* out = (float*)d_out;
  float* ws  = (float*)d_ws;

  // k_fps uses static LDS. k_grp dynamic (>64KB opt-in).
  size_t dyn_grp = (size_t)GRP_LDS_FLOATS * sizeof(float);  // ~131 KB
  hipFuncSetAttribute(reinterpret_cast<const void*>(k_grp),
                      hipFuncAttributeMaxDynamicSharedMemorySize, (int)dyn_grp);

  // invalidate k_fps sync slots (tag field 0xAAAA != any round); graph-safe.
  hipMemsetAsync(ws + WS_SYNC, 0xAA, (size_t)2 * 16 * SB * 8, stream);

  hipLaunchKernelGGL(k_fps, dim3(BB * SB), dim3(NT1), 0, stream,
                     points, out, ws);
  hipLaunchKernelGGL(k_grp, dim3(32), dim3(NT1), dyn_grp, stream,
                     points, ws, w1, b1, g1, be1, m1, v1, w2, b2);
  hipLaunchKernelGGL(k_encB, dim3(512), dim3(256), 0, stream,
                     ws, w3, b3, g2, be2, m2, v2);
  hipLaunchKernelGGL(k_encCb, dim3(768), dim3(256), 0, stream, ws, w4, b4, out);
}

// Round 14
// 465.809 us; speedup vs baseline: 6.4747x; 6.4747x over previous
//
#include <hip/hip_runtime.h>
#include <math.h>

#define BB   16
#define NN   32768
#define GG   128
#define KK   64
#define EDD  384
#define NT1  1024
#define PPT  32   // NN / NT1 (k_grp phases)
#define SB   16   // k_fps blocks per batch (R14: was 8; protocol unchanged)
#define SP   (NN / SB)   // 2048 points per k_fps block
#define JP   (SP / NT1)  // 2 points/thread

// ---- workspace layout (float offsets) ----
#define WS_GC     0          // [16][2][3]      = 96     (c0, cm per batch)
#define WS_F2     6240       // [32][256][64]   = 524288
#define WS_FG     530528     // [32][256]       = 8192
#define WS_F4     538720     // [32][512][64]   = 1048576
#define WS_SYNC   1587296    // u64 [2 parity][16 batch][16 blk] = 4 KB

// ---- k_grp LDS layout (float offsets past dkey[NN]) ----
#define GOFF_WSUM  (NN)        // uint [2][16] parity-buffered wave sums
#define GOFF_CNT   (NN + 32)   // int [8]: [0]=sel_cnt [1]=eq_cnt
#define GOFF_SEL   (NN + 40)   // int [64]
#define GOFF_EQB   (NN + 104)  // int [512]
#define GOFF_XL    (NN + 616)  // float [KK*3]
#define GRP_LDS_FLOATS (NN + 808)

__device__ __forceinline__ float sq3(float a, float b, float c) {
  // matches np: ((a*a + b*b) + c*c), no FMA contraction
  return __fadd_rn(__fadd_rn(__fmul_rn(a, a), __fmul_rn(b, b)), __fmul_rn(c, c));
}
__device__ __forceinline__ float dot3(float ax, float ay, float az,
                                      float bx, float by, float bz) {
  return __fadd_rn(__fadd_rn(__fmul_rn(ax, bx), __fmul_rn(ay, by)), __fmul_rn(az, bz));
}
__device__ __forceinline__ unsigned long long shfl_xor_u64(unsigned long long v,
                                                           int off) {
  unsigned lo = (unsigned)v, hi = (unsigned)(v >> 32);
  lo = __shfl_xor(lo, off);
  hi = __shfl_xor(hi, off);
  return ((unsigned long long)hi << 32) | lo;
}

// ---------------------------------------------------------------------------
// Kernel 1: FPS. R12's PROVEN sync protocol (intra-block parity redp reduce
// -> ONE agent-scope publish per block -> lanes<SB of wave0 spin with pure
// agent-scope loads -> winner via LDS) at SB=16, with barrier B replaced by
// an LDS winp TAG-SPIN.
// R13 post-mortem: sc0 "L2-hit" polling read STALE lines (remote agent
// store does not update the reader's L2) -- 10x regression. Reverted to
// pure agent-scope polls (R12: 253 us measured).
// Changes vs R12, both attacking the non-hop per-round terms:
//  (a) SB=16 (256 blocks, JP=2): halves compute/round again (R12 validated
//      this scaling: SB 4->8 matched the model). 1 block/CU @ ~27KB LDS =>
//      all co-resident; still 1 publish + 1 spinning wave per block.
//  (b) barrier B deleted: waves 1-15 tag-spin on LDS winp (tag = round it
//      embedded in the packed value; strictly increasing => no ABA). WAR on
//      redp fixed by parity-indexing redp[2][16]; barrier A orders redp
//      writes before wave0's reduce. Round it+1's winp write is gated by
//      barrier A(it+1), which requires all waves past their winp(it) read.
// Slot parity safety unchanged: round it+2's slot write happens only after
// this block read all round it+1 slots, which required every block's
// round-it read. u64-max keeps np.argmax first-max tie rule.
// ---------------------------------------------------------------------------
__global__ void __launch_bounds__(NT1) k_fps(const float* __restrict__ points,
                                             float* __restrict__ out,
                                             float* __restrict__ ws) {
  __shared__ float2 xyS[SP];                 // 16 KB
  __shared__ float  zS[SP];                  // 8 KB
  __shared__ float cent[GG * 3];
  __shared__ float darr[GG];
  __shared__ int msh[1];
  __shared__ unsigned long long redp[2][16];
  __shared__ unsigned long long winp;

  const int gb   = blockIdx.x;
  // co-XCD mapping: class c = gb&7, blk = (gb>>3)&15, b = c*2 + (gb>>7).
  // All 16 blocks of a batch share gb%8 => same XCD under round-robin.
  const int b    = (gb & 7) * 2 + (gb >> 7);
  const int blk  = (gb >> 3) & 15;
  const int t    = threadIdx.x;
  const int wave = t >> 6, lane = t & 63;
  const float* P = points + (size_t)b * NN * 3;
  const int base = blk * SP;
  unsigned long long* slots = (unsigned long long*)(ws + WS_SYNC);

  // stage slice coords (thread-owned slots) + init reg-resident dist
#pragma unroll
  for (int j = 0; j < JP; ++j) {
    int q = t + j * NT1;
    const float* pp = P + (size_t)(base + q) * 3;
    xyS[q] = make_float2(pp[0], pp[1]);
    zS[q]  = pp[2];
  }
  float dist[JP];
#pragma unroll
  for (int j = 0; j < JP; ++j) dist[j] = INFINITY;

  float cx = P[0], cy = P[1], cz = P[2];  // centroid 0 = point 0
  if (blk == 0 && t == 0) { cent[0] = cx; cent[1] = cy; cent[2] = cz; }
  if (t == 0) winp = 0ULL;  // tag 0 != any round >= 1
  __syncthreads();

  for (int it = 1; it < GG; ++it) {
    const int par = it & 1;
    float bd = -INFINITY; int bj = 0;
#pragma unroll
    for (int j = 0; j < JP; ++j) {
      int q = t + j * NT1;
      float2 xy = xyS[q];
      float  zz = zS[q];
      float dx = __fsub_rn(xy.x, cx);
      float dy = __fsub_rn(xy.y, cy);
      float dz = __fsub_rn(zz, cz);
      float d  = __fadd_rn(__fadd_rn(__fmul_rn(dx, dx), __fmul_rn(dy, dy)),
                           __fmul_rn(dz, dz));
      float nd = fminf(dist[j], d);
      dist[j] = nd;
      if (nd > bd) { bd = nd; bj = j; }  // ascending q + strict > => first-max
    }
    // pack: [d_bits(32) | it(16) | 0xFFFF - idx(16)]; u64 max = (max d,
    // tie min idx) = np.argmax first-max rule. idx = base+t+bj*1024 < 32768.
    unsigned long long bp =
        ((unsigned long long)__float_as_uint(bd) << 32) |
        ((unsigned)it << 16) |
        (unsigned)(0xFFFF - (base + t + (bj << 10)));
#pragma unroll
    for (int off = 1; off < 64; off <<= 1) {
      unsigned long long o = shfl_xor_u64(bp, off);
      if (o > bp) bp = o;
    }
    if (lane == 0) redp[par][wave] = bp;
    __syncthreads();  // barrier A (orders redp writes; the ONLY barrier)
    unsigned long long w;
    if (wave == 0) {
      unsigned long long v = redp[par][lane & 15];
#pragma unroll
      for (int off = 1; off < 16; off <<= 1) {
        unsigned long long o = shfl_xor_u64(v, off);
        if (o > v) v = o;
      }
      unsigned long long* sl = slots + ((size_t)par * 16 + b) * SB;
      if (lane == 0)
        __hip_atomic_store(&sl[blk], v, __ATOMIC_RELAXED,
                           __HIP_MEMORY_SCOPE_AGENT);
      if (lane < SB) {
        unsigned long long o;
        do {
          o = __hip_atomic_load(&sl[lane], __ATOMIC_RELAXED,
                                __HIP_MEMORY_SCOPE_AGENT);
        } while ((unsigned)((o >> 16) & 0xFFFF) != (unsigned)it);  // tag-spin
        unsigned long long o1 = shfl_xor_u64(o, 1);
        if (o1 > o) o = o1;
        unsigned long long o2 = shfl_xor_u64(o, 2);
        if (o2 > o) o = o2;
        unsigned long long o4 = shfl_xor_u64(o, 4);
        if (o4 > o) o = o4;
        unsigned long long o8 = shfl_xor_u64(o, 8);
        if (o8 > o) o = o8;
        if (lane == 0)
          __hip_atomic_store(&winp, o, __ATOMIC_RELAXED,
                             __HIP_MEMORY_SCOPE_WORKGROUP);
        w = o;
      }
      w = shfl_xor_u64(w, 0);  // no-op; all lanes<SB hold w, others below
      // broadcast within wave 0 (lanes >= SB need w too)
      {
        unsigned lo = (unsigned)w, hi = (unsigned)(w >> 32);
        lo = __shfl(lo, 0);
        hi = __shfl(hi, 0);
        w = ((unsigned long long)hi << 32) | lo;
      }
    } else {
      // LDS tag-spin replaces barrier B (tags strictly increase => no ABA)
      do {
        w = __hip_atomic_load(&winp, __ATOMIC_RELAXED,
                              __HIP_MEMORY_SCOPE_WORKGROUP);
      } while ((unsigned)((w >> 16) & 0xFFFF) != (unsigned)it);
    }
    int sv = 0xFFFF - (int)(w & 0xFFFF);
    const float* wp = P + (size_t)sv * 3;  // wave-uniform -> broadcast load
    cx = wp[0]; cy = wp[1]; cz = wp[2];
    if (blk == 0 && t == 0) {
      cent[it * 3 + 0] = cx; cent[it * 3 + 1] = cy; cent[it * 3 + 2] = cz;
    }
  }

  if (blk != 0) return;  // epilogue on block 0 of each batch only
  __syncthreads();

  // morton step 1: m = argmin_{j>=1} cdist(c0, cj), ref expansion formula
  if (t < GG) {
    float c0x = cent[0], c0y = cent[1], c0z = cent[2];
    float cjx = cent[t * 3 + 0], cjy = cent[t * 3 + 1], cjz = cent[t * 3 + 2];
    float sa = sq3(c0x, c0y, c0z);
    float sb = sq3(cjx, cjy, cjz);
    float dt = dot3(c0x, c0y, c0z, cjx, cjy, cjz);
    float dd = __fsub_rn(__fadd_rn(sa, sb), __fmul_rn(2.0f, dt));
    darr[t] = (t == 0) ? INFINITY : dd;
  }
  __syncthreads();
  if (t == 0) {
    float vd = darr[1]; int vi = 1;
    for (int j = 2; j < GG; ++j) {
      float od = darr[j];
      if (od < vd) { vd = od; vi = j; }  // strict < => first-min
    }
    msh[0] = vi;
    float* gc = ws + WS_GC + b * 6;
    gc[0] = cent[0];          gc[1] = cent[1];          gc[2] = cent[2];
    gc[3] = cent[vi * 3 + 0]; gc[4] = cent[vi * 3 + 1]; gc[5] = cent[vi * 3 + 2];
  }
  __syncthreads();
  int m = msh[0];
  // centroid output: pos0 = c0, pos1 = cm, pos>=2 = c0 (morton degeneracy)
  if (t < GG * 3) {
    int pos = t / 3, c = t % 3;
    float v = (pos == 1) ? cent[m * 3 + c] : cent[c];
    out[(size_t)b * GG * 3 + t] = v;
  }
}

// ---------------------------------------------------------------------------
// Kernel 2 (fused topk + encA): R9's binary-search selection (unchanged).
// Set-exact vs lax.top_k ((d,idx) lexicographic); encoder is k-permutation-
// invariant so set equality => identical output.
// ---------------------------------------------------------------------------
__global__ void __launch_bounds__(NT1) k_grp(
    const float* __restrict__ points, float* __restrict__ ws,
    const float* __restrict__ w1, const float* __restrict__ b1,
    const float* __restrict__ g1, const float* __restrict__ be1,
    const float* __restrict__ m1, const float* __restrict__ v1,
    const float* __restrict__ w2, const float* __restrict__ b2) {
  extern __shared__ float smem[];
  unsigned* dkey = (unsigned*)smem;          // [NN] keys; f1s overlays later
  float* f1s  = smem;                        // [128*65] = 8320 <= NN
  unsigned* wsum = (unsigned*)(smem + GOFF_WSUM);  // [2][16]
  int*   cnts = (int*)(smem + GOFF_CNT);     // [0]=sel_cnt [1]=eq_cnt
  int*   sel  = (int*)(smem + GOFF_SEL);     // [64]
  int*   eqb  = (int*)(smem + GOFF_EQB);     // [512]
  float* xl   = smem + GOFF_XL;              // [KK*3]

  const int g = blockIdx.x;
  const int b = g >> 1, which = g & 1;
  const int t = threadIdx.x;
  const int wave = t >> 6, lane = t & 63;
  const float* P = points + (size_t)b * NN * 3;
  const float* gc = ws + WS_GC + b * 6 + which * 3;
  const float cx = gc[0], cy = gc[1], cz = gc[2];
  const float sa = sq3(cx, cy, cz);

  // ---- phase 1: distances -> monotone uint keys in LDS ----
#pragma unroll
  for (int j = 0; j < PPT; ++j) {
    int p = t + j * NT1;
    const float* pp = P + (size_t)p * 3;
    float px = pp[0], py = pp[1], pz = pp[2];
    float sb = sq3(px, py, pz);
    float dt = dot3(cx, cy, cz, px, py, pz);
    float d  = __fsub_rn(__fadd_rn(sa, sb), __fmul_rn(2.0f, dt));
    unsigned u = __float_as_uint(d);
    dkey[p] = u ^ ((u & 0x80000000u) ? 0xFFFFFFFFu : 0x80000000u);
  }
  if (t < 2) cnts[t] = 0;
  __syncthreads();

  // ---- phase 2: binary search for K = min key with count(<=K) >= 64 ----
  unsigned klo = 0u, khi = 0xFFFFFFFFu;
  int par = 0;
  while (klo < khi) {  // uniform across block: 32 iterations
    unsigned mid = klo + ((khi - klo) >> 1);
    int c = 0;
#pragma unroll
    for (int j = 0; j < PPT; ++j) c += (dkey[t + j * NT1] <= mid) ? 1 : 0;
#pragma unroll
    for (int off = 1; off < 64; off <<= 1) c += __shfl_xor(c, off);
    if (lane == 0) wsum[par * 16 + wave] = (unsigned)c;
    __syncthreads();  // one barrier/iter; parity buffer kills WAR race
    int tot = 0;
#pragma unroll
    for (int w = 0; w < 16; ++w) tot += (int)wsum[par * 16 + w];
    if (tot >= KK) khi = mid; else klo = mid + 1;
    par ^= 1;
  }
  const unsigned K64 = klo;

  // count(< K64) — uniform C_lt
  {
    int c = 0;
#pragma unroll
    for (int j = 0; j < PPT; ++j) c += (dkey[t + j * NT1] < K64) ? 1 : 0;
#pragma unroll
    for (int off = 1; off < 64; off <<= 1) c += __shfl_xor(c, off);
    if (lane == 0) wsum[par * 16 + wave] = (unsigned)c;
    __syncthreads();
  }
  int C_lt = 0;
#pragma unroll
  for (int w = 0; w < 16; ++w) C_lt += (int)wsum[par * 16 + w];

  // ---- phase 3: collection (set-exact; order within sel arbitrary) ----
#pragma unroll
  for (int j = 0; j < PPT; ++j) {
    int p = t + j * NT1;
    unsigned kk = dkey[p];
    if (kk < K64) {
      int pos = atomicAdd(&cnts[0], 1);
      sel[pos] = p;
    } else if (kk == K64) {
      int pos = atomicAdd(&cnts[1], 1);
      if (pos < 512) eqb[pos] = p;
    }
  }
  __syncthreads();

  // ties: take (KK - C_lt) smallest INDICES among key==K64 (top_k rule)
  if (wave == 0) {
    int M = cnts[1]; if (M > 512) M = 512;
    int R = KK - C_lt;  // >=1 by minimality of K64
    int e[8];
#pragma unroll
    for (int q = 0; q < 8; ++q) {
      int ix = lane + q * 64;
      e[q] = (ix < M) ? eqb[ix] : 0x7FFFFFFF;
    }
    for (int r = 0; r < R; ++r) {
      int gm = e[0];
#pragma unroll
      for (int q = 1; q < 8; ++q) gm = min(gm, e[q]);
#pragma unroll
      for (int off = 1; off < 64; off <<= 1) gm = min(gm, __shfl_xor(gm, off));
      if (lane == 0) sel[C_lt + r] = gm;
#pragma unroll
      for (int q = 0; q < 8; ++q) if (e[q] == gm) e[q] = 0x7FFFFFFF;
    }
  }
  __syncthreads();

  if (t < KK) {  // local coords of the 64 selected into LDS
    int p = sel[t];
    const float* pp = P + (size_t)p * 3;
    xl[t * 3 + 0] = __fsub_rn(pp[0], cx);
    xl[t * 3 + 1] = __fsub_rn(pp[1], cy);
    xl[t * 3 + 2] = __fsub_rn(pp[2], cz);
  }
  __syncthreads();  // dkey dead after this point; f1s overlays it

  // ---- phase 4: f1 = relu(bn1(w1@x + b1)) -> f1s[128][65] ----
  {
    const int o = t & 127, kh = t >> 7;  // kh in [0,8)
    float wx = w1[o * 3 + 0], wy = w1[o * 3 + 1], wz = w1[o * 3 + 2];
    float inv = g1[o] * (1.0f / sqrtf(v1[o] + 1e-5f));
    float add = be1[o] - m1[o] * inv;
    float bb = b1[o];
#pragma unroll
    for (int kk = 0; kk < 8; ++kk) {
      int k = kh * 8 + kk;
      float f = fmaf(wx, xl[k * 3 + 0],
                fmaf(wy, xl[k * 3 + 1],
                fmaf(wz, xl[k * 3 + 2], bb)));
      f = fmaf(f, inv, add);
      f1s[o * 65 + k] = fmaxf(f, 0.0f);
    }
  }
  __syncthreads();

  // ---- phase 5: f2 = w2@f1 + b2 -> global; fg = max_k -> global ----
  const int k  = t & 63;
  const int og = __builtin_amdgcn_readfirstlane(t >> 6);  // wave-uniform [0,16)
  const int o0 = og * 16;
  float acc[16];
#pragma unroll
  for (int oo = 0; oo < 16; ++oo) acc[oo] = b2[o0 + oo];
  for (int i = 0; i < 128; ++i) {
    float xv = f1s[i * 65 + k];
#pragma unroll
    for (int oo = 0; oo < 16; ++oo)
      acc[oo] = fmaf(w2[(o0 + oo) * 128 + i], xv, acc[oo]);  // uniform -> s_load
  }
  float* f2g = ws + WS_F2 + (size_t)g * 256 * 64;
  float* fgg = ws + WS_FG + g * 256;
#pragma unroll
  for (int oo = 0; oo < 16; ++oo) f2g[(o0 + oo) * 64 + k] = acc[oo];
#pragma unroll
  for (int oo = 0; oo < 16; ++oo) {
    float v = acc[oo];
#pragma unroll
    for (int off = 1; off < 64; off <<= 1) v = fmaxf(v, __shfl_xor(v, off));
    if (k == 0) fgg[o0 + oo] = v;
  }
}

// ---------------------------------------------------------------------------
// Kernel 3 (stage B): f4 = relu(bn2(w3 @ concat([fg bcast, f2]) + b3))
// grid = 32 groups x 16 o-chunks of 32. (unchanged)
// ---------------------------------------------------------------------------
__global__ void __launch_bounds__(256) k_encB(
    float* __restrict__ ws,
    const float* __restrict__ w3, const float* __restrict__ b3,
    const float* __restrict__ g2, const float* __restrict__ be2,
    const float* __restrict__ m2, const float* __restrict__ v2) {
  __shared__ float part[32][8];
  __shared__ float sfg[32];
  const int blk = blockIdx.x;
  const int g = blk >> 4, oc = blk & 15;
  const int t = threadIdx.x;
  const int k = t & 63;
  const int og = __builtin_amdgcn_readfirstlane(t >> 6);  // [0,4)
  const int ob = oc * 32;
  const float* fgg = ws + WS_FG + g * 256;
  {
    int o = t >> 3, ih = t & 7;
    float s = 0.0f;
    int i0 = ih * 32;
    for (int ii = 0; ii < 32; ++ii) {
      int i = i0 + ii;
      s = fmaf(w3[(size_t)(ob + o) * 512 + i], fgg[i], s);
    }
    part[o][ih] = s;
  }
  __syncthreads();
  if (t < 32) {
    float s = ((part[t][0] + part[t][1]) + (part[t][2] + part[t][3])) +
              ((part[t][4] + part[t][5]) + (part[t][6] + part[t][7]));
    sfg[t] = b3[ob + t] + s;
  }
  __syncthreads();
  const int o0 = ob + og * 8;
  float acc[8];
#pragma unroll
  for (int oo = 0; oo < 8; ++oo) acc[oo] = sfg[og * 8 + oo];
  const float* f2g = ws + WS_F2 + (size_t)g * 256 * 64;
#pragma unroll 4
  for (int i = 0; i < 256; ++i) {
    float xv = f2g[i * 64 + k];
#pragma unroll
    for (int oo = 0; oo < 8; ++oo)
      acc[oo] = fmaf(w3[(size_t)(o0 + oo) * 512 + 256 + i], xv, acc[oo]);
  }
  float* f4g = ws + WS_F4 + (size_t)g * 512 * 64;
#pragma unroll
  for (int oo = 0; oo < 8; ++oo) {
    int o = o0 + oo;
    float inv = g2[o] * (1.0f / sqrtf(v2[o] + 1e-5f));
    float add = be2[o] - m2[o] * inv;
    f4g[o * 64 + k] = fmaxf(fmaf(acc[oo], inv, add), 0.0f);
  }
}

// ---------------------------------------------------------------------------
// Kernel 4 (fused stage C + broadcast): token = max_k (w4 @ f4 + b4).
// grid = 32 x 24 chunks of 16. (unchanged)
// ---------------------------------------------------------------------------
__global__ void __launch_bounds__(256) k_encCb(float* __restrict__ ws,
                                               const float* __restrict__ w4,
                                               const float* __restrict__ b4,
                                               float* __restrict__ out) {
  const int blk = blockIdx.x;
  const int g = blk / 24, oc = blk % 24;
  const int b = g >> 1, which = g & 1;
  const int t = threadIdx.x;
  const int k = t & 63;
  const int og = __builtin_amdgcn_readfirstlane(t >> 6);
  const int o0 = oc * 16 + og * 4;
  float acc[4];
#pragma unroll
  for (int oo = 0; oo < 4; ++oo) acc[oo] = b4[o0 + oo];
  const float* f4g = ws + WS_F4 + (size_t)g * 512 * 64;
#pragma unroll 8
  for (int i = 0; i < 512; ++i) {
    float xv = f4g[i * 64 + k];
#pragma unroll
    for (int oo = 0; oo < 4; ++oo)
      acc[oo] = fmaf(w4[(size_t)(o0 + oo) * 512 + i], xv, acc[oo]);
  }
#pragma unroll
  for (int oo = 0; oo < 4; ++oo) {
#pragma unroll
    for (int off = 1; off < 64; off <<= 1)
      acc[oo] = fmaxf(acc[oo], __shfl_xor(acc[oo], off));
  }
  float* tok = out + (size_t)BB * GG * 3;
  if (which == 1) {
    if (k == 0) {
      float* dst = tok + ((size_t)b * GG + 1) * EDD + o0;
#pragma unroll
      for (int oo = 0; oo < 4; ++oo) dst[oo] = acc[oo];
    }
  } else {
#pragma unroll
    for (int rep = 0; rep < 2; ++rep) {
      int pos = k + rep * 64;
      if (pos == 1) continue;
      float* dst = tok + ((size_t)b * GG + pos) * EDD + o0;
#pragma unroll
      for (int oo = 0; oo < 4; ++oo) dst[oo] = acc[oo];
    }
  }
}

extern "C" void kernel_launch(void* const* d_in, const int* in_sizes, int n_in,
                              void* d_out, int out_size, void* d_ws, size_t ws_size,
                              hipStream_t stream) {
  const float* points = (const float*)d_in[0];
  const float* w1  = (const float*)d_in[1];
  const float* b1  = (const float*)d_in[2];
  const float* g1  = (const float*)d_in[3];
  const float* be1 = (const float*)d_in[4];
  const float* m1  = (const float*)d_in[5];
  const float* v1  = (const float*)d_in[6];
  const float* w2  = (const float*)d_in[7];
  const float* b2  = (const float*)d_in[8];
  const float* w3  = (const float*)d_in[9];
  const float* b3  = (const float*)d_in[10];
  const float* g2  = (const float*)d_in[11];
  const float* be2 = (const float*)d_in[12];
  const float* m2  = (const float*)d_in[13];
  const float* v2  = (const float*)d_in[14];
  const float* w4  = (const float*)d_in[15];
  const float* b4  = (const float*)d_in[16];
  float* out = (float*)d_out;
  float* ws  = (float*)d_ws;

  // k_fps uses static LDS. k_grp dynamic (>64KB opt-in).
  size_t dyn_grp = (size_t)GRP_LDS_FLOATS * sizeof(float);  // ~131 KB
  hipFuncSetAttribute(reinterpret_cast<const void*>(k_grp),
                      hipFuncAttributeMaxDynamicSharedMemorySize, (int)dyn_grp);

  // invalidate k_fps sync slots (tag field 0xAAAA != any round); graph-safe.
  hipMemsetAsync(ws + WS_SYNC, 0xAA, (size_t)2 * 16 * SB * 8, stream);

  hipLaunchKernelGGL(k_fps, dim3(BB * SB), dim3(NT1), 0, stream,
                     points, out, ws);
  hipLaunchKernelGGL(k_grp, dim3(32), dim3(NT1), dyn_grp, stream,
                     points, ws, w1, b1, g1, be1, m1, v1, w2, b2);
  hipLaunchKernelGGL(k_encB, dim3(512), dim3(256), 0, stream,
                     ws, w3, b3, g2, be2, m2, v2);
  hipLaunchKernelGGL(k_encCb, dim3(768), dim3(256), 0, stream, ws, w4, b4, out);
}

// Round 15
// 451.503 us; speedup vs baseline: 6.6798x; 1.0317x over previous
//
#include <hip/hip_runtime.h>
#include <math.h>

#define BB   16
#define NN   32768
#define GG   128
#define KK   64
#define EDD  384
#define NT1  1024
#define PPT  32   // NN / NT1 (k_grp phases)
#define SB   16   // k_fps blocks per batch
#define SP   (NN / SB)   // 2048 points per k_fps block
#define JP   (SP / NT1)  // 2 points/thread

// ---- workspace layout (float offsets) ----
#define WS_GC     0          // [16][2][3]      = 96     (c0, cm per batch)
#define WS_F2     6240       // [32][256][64]   = 524288
#define WS_FG     530528     // [32][256]       = 8192
#define WS_F4     538720     // [32][512][64]   = 1048576
#define WS_SYNC   1587296    // u64 [2 parity][16 batch][16 blk] = 4 KB

// ---- k_grp LDS layout (float/uint offsets past dkey[NN]) ----
#define GOFF_HIST  (NN)           // uint [16][256] per-wave histograms = 4096
#define GOFF_HSUM  (NN + 4096)    // uint [256] reduced histogram
#define GOFF_CNT   (NN + 4352)    // int [8]: [0]=sel_cnt [1]=eq_cnt [2]=selB [3]=selCum
#define GOFF_SEL   (NN + 4360)    // int [64]
#define GOFF_EQB   (NN + 4424)    // int [512]
#define GOFF_XL    (NN + 4936)    // float [KK*3]
#define GRP_LDS_FLOATS (NN + 5128)  // 37896 floats = 151.6 KB (<160 KB)

__device__ __forceinline__ float sq3(float a, float b, float c) {
  // matches np: ((a*a + b*b) + c*c), no FMA contraction
  return __fadd_rn(__fadd_rn(__fmul_rn(a, a), __fmul_rn(b, b)), __fmul_rn(c, c));
}
__device__ __forceinline__ float dot3(float ax, float ay, float az,
                                      float bx, float by, float bz) {
  return __fadd_rn(__fadd_rn(__fmul_rn(ax, bx), __fmul_rn(ay, by)), __fmul_rn(az, bz));
}
__device__ __forceinline__ unsigned long long shfl_xor_u64(unsigned long long v,
                                                           int off) {
  unsigned lo = (unsigned)v, hi = (unsigned)(v >> 32);
  lo = __shfl_xor(lo, off);
  hi = __shfl_xor(hi, off);
  return ((unsigned long long)hi << 32) | lo;
}

// ---------------------------------------------------------------------------
// Kernel 1: FPS — UNCHANGED from R14 (measured 253.6 us; per-round pinned at
// the ~2.0us agent-scope hop floor: SB=8 vs 16 and barrier-B removal were
// nulls, so this is the sync-latency roofline for this protocol).
// ---------------------------------------------------------------------------
__global__ void __launch_bounds__(NT1) k_fps(const float* __restrict__ points,
                                             float* __restrict__ out,
                                             float* __restrict__ ws) {
  __shared__ float2 xyS[SP];                 // 16 KB
  __shared__ float  zS[SP];                  // 8 KB
  __shared__ float cent[GG * 3];
  __shared__ float darr[GG];
  __shared__ int msh[1];
  __shared__ unsigned long long redp[2][16];
  __shared__ unsigned long long winp;

  const int gb   = blockIdx.x;
  // co-XCD mapping: class c = gb&7, blk = (gb>>3)&15, b = c*2 + (gb>>7).
  const int b    = (gb & 7) * 2 + (gb >> 7);
  const int blk  = (gb >> 3) & 15;
  const int t    = threadIdx.x;
  const int wave = t >> 6, lane = t & 63;
  const float* P = points + (size_t)b * NN * 3;
  const int base = blk * SP;
  unsigned long long* slots = (unsigned long long*)(ws + WS_SYNC);

#pragma unroll
  for (int j = 0; j < JP; ++j) {
    int q = t + j * NT1;
    const float* pp = P + (size_t)(base + q) * 3;
    xyS[q] = make_float2(pp[0], pp[1]);
    zS[q]  = pp[2];
  }
  float dist[JP];
#pragma unroll
  for (int j = 0; j < JP; ++j) dist[j] = INFINITY;

  float cx = P[0], cy = P[1], cz = P[2];  // centroid 0 = point 0
  if (blk == 0 && t == 0) { cent[0] = cx; cent[1] = cy; cent[2] = cz; }
  if (t == 0) winp = 0ULL;  // tag 0 != any round >= 1
  __syncthreads();

  for (int it = 1; it < GG; ++it) {
    const int par = it & 1;
    float bd = -INFINITY; int bj = 0;
#pragma unroll
    for (int j = 0; j < JP; ++j) {
      int q = t + j * NT1;
      float2 xy = xyS[q];
      float  zz = zS[q];
      float dx = __fsub_rn(xy.x, cx);
      float dy = __fsub_rn(xy.y, cy);
      float dz = __fsub_rn(zz, cz);
      float d  = __fadd_rn(__fadd_rn(__fmul_rn(dx, dx), __fmul_rn(dy, dy)),
                           __fmul_rn(dz, dz));
      float nd = fminf(dist[j], d);
      dist[j] = nd;
      if (nd > bd) { bd = nd; bj = j; }  // ascending q + strict > => first-max
    }
    unsigned long long bp =
        ((unsigned long long)__float_as_uint(bd) << 32) |
        ((unsigned)it << 16) |
        (unsigned)(0xFFFF - (base + t + (bj << 10)));
#pragma unroll
    for (int off = 1; off < 64; off <<= 1) {
      unsigned long long o = shfl_xor_u64(bp, off);
      if (o > bp) bp = o;
    }
    if (lane == 0) redp[par][wave] = bp;
    __syncthreads();  // barrier A (orders redp writes; the ONLY barrier)
    unsigned long long w;
    if (wave == 0) {
      unsigned long long v = redp[par][lane & 15];
#pragma unroll
      for (int off = 1; off < 16; off <<= 1) {
        unsigned long long o = shfl_xor_u64(v, off);
        if (o > v) v = o;
      }
      unsigned long long* sl = slots + ((size_t)par * 16 + b) * SB;
      if (lane == 0)
        __hip_atomic_store(&sl[blk], v, __ATOMIC_RELAXED,
                           __HIP_MEMORY_SCOPE_AGENT);
      if (lane < SB) {
        unsigned long long o;
        do {
          o = __hip_atomic_load(&sl[lane], __ATOMIC_RELAXED,
                                __HIP_MEMORY_SCOPE_AGENT);
        } while ((unsigned)((o >> 16) & 0xFFFF) != (unsigned)it);  // tag-spin
        unsigned long long o1 = shfl_xor_u64(o, 1);
        if (o1 > o) o = o1;
        unsigned long long o2 = shfl_xor_u64(o, 2);
        if (o2 > o) o = o2;
        unsigned long long o4 = shfl_xor_u64(o, 4);
        if (o4 > o) o = o4;
        unsigned long long o8 = shfl_xor_u64(o, 8);
        if (o8 > o) o = o8;
        if (lane == 0)
          __hip_atomic_store(&winp, o, __ATOMIC_RELAXED,
                             __HIP_MEMORY_SCOPE_WORKGROUP);
        w = o;
      }
      {
        unsigned lo = (unsigned)w, hi = (unsigned)(w >> 32);
        lo = __shfl(lo, 0);
        hi = __shfl(hi, 0);
        w = ((unsigned long long)hi << 32) | lo;
      }
    } else {
      // LDS tag-spin replaces barrier B (tags strictly increase => no ABA)
      do {
        w = __hip_atomic_load(&winp, __ATOMIC_RELAXED,
                              __HIP_MEMORY_SCOPE_WORKGROUP);
      } while ((unsigned)((w >> 16) & 0xFFFF) != (unsigned)it);
    }
    int sv = 0xFFFF - (int)(w & 0xFFFF);
    const float* wp = P + (size_t)sv * 3;  // wave-uniform -> broadcast load
    cx = wp[0]; cy = wp[1]; cz = wp[2];
    if (blk == 0 && t == 0) {
      cent[it * 3 + 0] = cx; cent[it * 3 + 1] = cy; cent[it * 3 + 2] = cz;
    }
  }

  if (blk != 0) return;  // epilogue on block 0 of each batch only
  __syncthreads();

  if (t < GG) {
    float c0x = cent[0], c0y = cent[1], c0z = cent[2];
    float cjx = cent[t * 3 + 0], cjy = cent[t * 3 + 1], cjz = cent[t * 3 + 2];
    float sa = sq3(c0x, c0y, c0z);
    float sb = sq3(cjx, cjy, cjz);
    float dt = dot3(c0x, c0y, c0z, cjx, cjy, cjz);
    float dd = __fsub_rn(__fadd_rn(sa, sb), __fmul_rn(2.0f, dt));
    darr[t] = (t == 0) ? INFINITY : dd;
  }
  __syncthreads();
  if (t == 0) {
    float vd = darr[1]; int vi = 1;
    for (int j = 2; j < GG; ++j) {
      float od = darr[j];
      if (od < vd) { vd = od; vi = j; }  // strict < => first-min
    }
    msh[0] = vi;
    float* gc = ws + WS_GC + b * 6;
    gc[0] = cent[0];          gc[1] = cent[1];          gc[2] = cent[2];
    gc[3] = cent[vi * 3 + 0]; gc[4] = cent[vi * 3 + 1]; gc[5] = cent[vi * 3 + 2];
  }
  __syncthreads();
  int m = msh[0];
  if (t < GG * 3) {
    int pos = t / 3, c = t % 3;
    float v = (pos == 1) ? cent[m * 3 + c] : cent[c];
    out[(size_t)b * GG * 3 + t] = v;
  }
}

// ---------------------------------------------------------------------------
// Kernel 2 (fused topk + encA). R15: selection via 4-pass RADIX-SELECT
// (byte per pass, MSB->LSB) instead of 32-step binary search: 4 full scans +
// ~16 barriers replace 33 scans + 33 barriers. Per-wave LDS histograms
// (16x256) cut same-address atomic contention 16x; wave0 does the 256-bucket
// prefix-scan + bucket pick. Produces the EXACT K64 (64th-smallest key) and
// C_lt (count < K64); collection + index-ordered tie resolution unchanged =>
// same set as lax.top_k ((d,idx) lexicographic) => identical output (encoder
// is k-permutation-invariant).
// ---------------------------------------------------------------------------
__global__ void __launch_bounds__(NT1) k_grp(
    const float* __restrict__ points, float* __restrict__ ws,
    const float* __restrict__ w1, const float* __restrict__ b1,
    const float* __restrict__ g1, const float* __restrict__ be1,
    const float* __restrict__ m1, const float* __restrict__ v1,
    const float* __restrict__ w2, const float* __restrict__ b2) {
  extern __shared__ float smem[];
  unsigned* dkey = (unsigned*)smem;          // [NN] keys; f1s overlays later
  float* f1s  = smem;                        // [128*65] = 8320 <= NN
  unsigned* histw = (unsigned*)(smem + GOFF_HIST);  // [16][256]
  unsigned* hsum  = (unsigned*)(smem + GOFF_HSUM);  // [256]
  int*   cnts = (int*)(smem + GOFF_CNT);     // [0]=sel [1]=eq [2]=selB [3]=selCum
  int*   sel  = (int*)(smem + GOFF_SEL);     // [64]
  int*   eqb  = (int*)(smem + GOFF_EQB);     // [512]
  float* xl   = smem + GOFF_XL;              // [KK*3]

  const int g = blockIdx.x;
  const int b = g >> 1, which = g & 1;
  const int t = threadIdx.x;
  const int wave = t >> 6, lane = t & 63;
  const float* P = points + (size_t)b * NN * 3;
  const float* gc = ws + WS_GC + b * 6 + which * 3;
  const float cx = gc[0], cy = gc[1], cz = gc[2];
  const float sa = sq3(cx, cy, cz);

  // ---- phase 1: distances -> monotone uint keys in LDS ----
#pragma unroll
  for (int j = 0; j < PPT; ++j) {
    int p = t + j * NT1;
    const float* pp = P + (size_t)p * 3;
    float px = pp[0], py = pp[1], pz = pp[2];
    float sb = sq3(px, py, pz);
    float dt = dot3(cx, cy, cz, px, py, pz);
    float d  = __fsub_rn(__fadd_rn(sa, sb), __fmul_rn(2.0f, dt));
    unsigned u = __float_as_uint(d);
    dkey[p] = u ^ ((u & 0x80000000u) ? 0xFFFFFFFFu : 0x80000000u);
  }
  if (t < 2) cnts[t] = 0;
  __syncthreads();

  // ---- phase 2: 4-pass radix-select for K64 (64th smallest key) ----
  unsigned prefix = 0u;
  int cnt_before = 0;  // block-uniform (recomputed from LDS each pass)
#pragma unroll
  for (int dpass = 0; dpass < 4; ++dpass) {
    const int s = 24 - 8 * dpass;
    // clear per-wave histograms (16*256 = 4096 words)
#pragma unroll
    for (int i = 0; i < 4; ++i) histw[t + i * NT1] = 0u;
    __syncthreads();
    // histogram keys matching current prefix (d==0: all match)
    unsigned* myh = histw + wave * 256;
#pragma unroll
    for (int j = 0; j < PPT; ++j) {
      unsigned key = dkey[t + j * NT1];
      bool match = (dpass == 0) || (((key ^ prefix) >> (s + 8)) == 0u);
      if (match) atomicAdd(&myh[(key >> s) & 0xFFu], 1u);
    }
    __syncthreads();
    // reduce 16 wave-hists -> hsum[256]
    if (t < 256) {
      unsigned c = 0;
#pragma unroll
      for (int w = 0; w < 16; ++w) c += histw[w * 256 + t];
      hsum[t] = c;
    }
    __syncthreads();
    // wave0: prefix-scan 256 buckets (4/lane) + pick crossing bucket
    if (wave == 0) {
      unsigned c0 = hsum[lane * 4 + 0], c1 = hsum[lane * 4 + 1];
      unsigned c2 = hsum[lane * 4 + 2], c3 = hsum[lane * 4 + 3];
      unsigned lsum = c0 + c1 + c2 + c3;
      unsigned inc = lsum;
#pragma unroll
      for (int off = 1; off < 64; off <<= 1) {
        unsigned o = __shfl_up(inc, off);
        if (lane >= off) inc += o;
      }
      unsigned excl = inc - lsum;
      int T = KK - cnt_before;  // >= 1
      if ((int)excl < T && (int)(excl + lsum) >= T) {  // exactly one lane
        unsigned cum = excl;
        int B;
        if ((int)(cum + c0) >= T) { B = lane * 4 + 0; }
        else if ((int)(cum + c0 + c1) >= T) { B = lane * 4 + 1; cum += c0; }
        else if ((int)(cum + c0 + c1 + c2) >= T) { B = lane * 4 + 2; cum += c0 + c1; }
        else { B = lane * 4 + 3; cum += c0 + c1 + c2; }
        cnts[2] = B;
        cnts[3] = cnt_before + (int)cum;
      }
    }
    __syncthreads();
    prefix |= ((unsigned)cnts[2]) << s;
    cnt_before = cnts[3];
    __syncthreads();  // cnts[2]/[3] consumed before next pass overwrites
  }
  const unsigned K64 = prefix;
  const int C_lt = cnt_before;

  // ---- phase 3: collection (set-exact; order within sel arbitrary) ----
#pragma unroll
  for (int j = 0; j < PPT; ++j) {
    int p = t + j * NT1;
    unsigned kk = dkey[p];
    if (kk < K64) {
      int pos = atomicAdd(&cnts[0], 1);
      sel[pos] = p;
    } else if (kk == K64) {
      int pos = atomicAdd(&cnts[1], 1);
      if (pos < 512) eqb[pos] = p;
    }
  }
  __syncthreads();

  // ties: take (KK - C_lt) smallest INDICES among key==K64 (top_k rule)
  if (wave == 0) {
    int M = cnts[1]; if (M > 512) M = 512;
    int R = KK - C_lt;  // >=1 by minimality of K64
    int e[8];
#pragma unroll
    for (int q = 0; q < 8; ++q) {
      int ix = lane + q * 64;
      e[q] = (ix < M) ? eqb[ix] : 0x7FFFFFFF;
    }
    for (int r = 0; r < R; ++r) {
      int gm = e[0];
#pragma unroll
      for (int q = 1; q < 8; ++q) gm = min(gm, e[q]);
#pragma unroll
      for (int off = 1; off < 64; off <<= 1) gm = min(gm, __shfl_xor(gm, off));
      if (lane == 0) sel[C_lt + r] = gm;
#pragma unroll
      for (int q = 0; q < 8; ++q) if (e[q] == gm) e[q] = 0x7FFFFFFF;
    }
  }
  __syncthreads();

  if (t < KK) {  // local coords of the 64 selected into LDS
    int p = sel[t];
    const float* pp = P + (size_t)p * 3;
    xl[t * 3 + 0] = __fsub_rn(pp[0], cx);
    xl[t * 3 + 1] = __fsub_rn(pp[1], cy);
    xl[t * 3 + 2] = __fsub_rn(pp[2], cz);
  }
  __syncthreads();  // dkey dead after this point; f1s overlays it

  // ---- phase 4: f1 = relu(bn1(w1@x + b1)) -> f1s[128][65] ----
  {
    const int o = t & 127, kh = t >> 7;  // kh in [0,8)
    float wx = w1[o * 3 + 0], wy = w1[o * 3 + 1], wz = w1[o * 3 + 2];
    float inv = g1[o] * (1.0f / sqrtf(v1[o] + 1e-5f));
    float add = be1[o] - m1[o] * inv;
    float bb = b1[o];
#pragma unroll
    for (int kk = 0; kk < 8; ++kk) {
      int k = kh * 8 + kk;
      float f = fmaf(wx, xl[k * 3 + 0],
                fmaf(wy, xl[k * 3 + 1],
                fmaf(wz, xl[k * 3 + 2], bb)));
      f = fmaf(f, inv, add);
      f1s[o * 65 + k] = fmaxf(f, 0.0f);
    }
  }
  __syncthreads();

  // ---- phase 5: f2 = w2@f1 + b2 -> global; fg = max_k -> global ----
  const int k  = t & 63;
  const int og = __builtin_amdgcn_readfirstlane(t >> 6);  // wave-uniform [0,16)
  const int o0 = og * 16;
  float acc[16];
#pragma unroll
  for (int oo = 0; oo < 16; ++oo) acc[oo] = b2[o0 + oo];
  for (int i = 0; i < 128; ++i) {
    float xv = f1s[i * 65 + k];
#pragma unroll
    for (int oo = 0; oo < 16; ++oo)
      acc[oo] = fmaf(w2[(o0 + oo) * 128 + i], xv, acc[oo]);  // uniform -> s_load
  }
  float* f2g = ws + WS_F2 + (size_t)g * 256 * 64;
  float* fgg = ws + WS_FG + g * 256;
#pragma unroll
  for (int oo = 0; oo < 16; ++oo) f2g[(o0 + oo) * 64 + k] = acc[oo];
#pragma unroll
  for (int oo = 0; oo < 16; ++oo) {
    float v = acc[oo];
#pragma unroll
    for (int off = 1; off < 64; off <<= 1) v = fmaxf(v, __shfl_xor(v, off));
    if (k == 0) fgg[o0 + oo] = v;
  }
}

// ---------------------------------------------------------------------------
// Kernel 3 (stage B): f4 = relu(bn2(w3 @ concat([fg bcast, f2]) + b3))
// grid = 32 groups x 16 o-chunks of 32. (unchanged)
// ---------------------------------------------------------------------------
__global__ void __launch_bounds__(256) k_encB(
    float* __restrict__ ws,
    const float* __restrict__ w3, const float* __restrict__ b3,
    const float* __restrict__ g2, const float* __restrict__ be2,
    const float* __restrict__ m2, const float* __restrict__ v2) {
  __shared__ float part[32][8];
  __shared__ float sfg[32];
  const int blk = blockIdx.x;
  const int g = blk >> 4, oc = blk & 15;
  const int t = threadIdx.x;
  const int k = t & 63;
  const int og = __builtin_amdgcn_readfirstlane(t >> 6);  // [0,4)
  const int ob = oc * 32;
  const float* fgg = ws + WS_FG + g * 256;
  {
    int o = t >> 3, ih = t & 7;
    float s = 0.0f;
    int i0 = ih * 32;
    for (int ii = 0; ii < 32; ++ii) {
      int i = i0 + ii;
      s = fmaf(w3[(size_t)(ob + o) * 512 + i], fgg[i], s);
    }
    part[o][ih] = s;
  }
  __syncthreads();
  if (t < 32) {
    float s = ((part[t][0] + part[t][1]) + (part[t][2] + part[t][3])) +
              ((part[t][4] + part[t][5]) + (part[t][6] + part[t][7]));
    sfg[t] = b3[ob + t] + s;
  }
  __syncthreads();
  const int o0 = ob + og * 8;
  float acc[8];
#pragma unroll
  for (int oo = 0; oo < 8; ++oo) acc[oo] = sfg[og * 8 + oo];
  const float* f2g = ws + WS_F2 + (size_t)g * 256 * 64;
#pragma unroll 4
  for (int i = 0; i < 256; ++i) {
    float xv = f2g[i * 64 + k];
#pragma unroll
    for (int oo = 0; oo < 8; ++oo)
      acc[oo] = fmaf(w3[(size_t)(o0 + oo) * 512 + 256 + i], xv, acc[oo]);
  }
  float* f4g = ws + WS_F4 + (size_t)g * 512 * 64;
#pragma unroll
  for (int oo = 0; oo < 8; ++oo) {
    int o = o0 + oo;
    float inv = g2[o] * (1.0f / sqrtf(v2[o] + 1e-5f));
    float add = be2[o] - m2[o] * inv;
    f4g[o * 64 + k] = fmaxf(fmaf(acc[oo], inv, add), 0.0f);
  }
}

// ---------------------------------------------------------------------------
// Kernel 4 (fused stage C + broadcast): token = max_k (w4 @ f4 + b4).
// grid = 32 x 24 chunks of 16. (unchanged)
// ---------------------------------------------------------------------------
__global__ void __launch_bounds__(256) k_encCb(float* __restrict__ ws,
                                               const float* __restrict__ w4,
                                               const float* __restrict__ b4,
                                               float* __restrict__ out) {
  const int blk = blockIdx.x;
  const int g = blk / 24, oc = blk % 24;
  const int b = g >> 1, which = g & 1;
  const int t = threadIdx.x;
  const int k = t & 63;
  const int og = __builtin_amdgcn_readfirstlane(t >> 6);
  const int o0 = oc * 16 + og * 4;
  float acc[4];
#pragma unroll
  for (int oo = 0; oo < 4; ++oo) acc[oo] = b4[o0 + oo];
  const float* f4g = ws + WS_F4 + (size_t)g * 512 * 64;
#pragma unroll 8
  for (int i = 0; i < 512; ++i) {
    float xv = f4g[i * 64 + k];
#pragma unroll
    for (int oo = 0; oo < 4; ++oo)
      acc[oo] = fmaf(w4[(size_t)(o0 + oo) * 512 + i], xv, acc[oo]);
  }
#pragma unroll
  for (int oo = 0; oo < 4; ++oo) {
#pragma unroll
    for (int off = 1; off < 64; off <<= 1)
      acc[oo] = fmaxf(acc[oo], __shfl_xor(acc[oo], off));
  }
  float* tok = out + (size_t)BB * GG * 3;
  if (which == 1) {
    if (k == 0) {
      float* dst = tok + ((size_t)b * GG + 1) * EDD + o0;
#pragma unroll
      for (int oo = 0; oo < 4; ++oo) dst[oo] = acc[oo];
    }
  } else {
#pragma unroll
    for (int rep = 0; rep < 2; ++rep) {
      int pos = k + rep * 64;
      if (pos == 1) continue;
      float* dst = tok + ((size_t)b * GG + pos) * EDD + o0;
#pragma unroll
      for (int oo = 0; oo < 4; ++oo) dst[oo] = acc[oo];
    }
  }
}

extern "C" void kernel_launch(void* const* d_in, const int* in_sizes, int n_in,
                              void* d_out, int out_size, void* d_ws, size_t ws_size,
                              hipStream_t stream) {
  const float* points = (const float*)d_in[0];
  const float* w1  = (const float*)d_in[1];
  const float* b1  = (const float*)d_in[2];
  const float* g1  = (const float*)d_in[3];
  const float* be1 = (const float*)d_in[4];
  const float* m1  = (const float*)d_in[5];
  const float* v1  = (const float*)d_in[6];
  const float* w2  = (const float*)d_in[7];
  const float* b2  = (const float*)d_in[8];
  const float* w3  = (const float*)d_in[9];
  const float* b3  = (const float*)d_in[10];
  const float* g2  = (const float*)d_in[11];
  const float* be2 = (const float*)d_in[12];
  const float* m2  = (const float*)d_in[13];
  const float* v2  = (const float*)d_in[14];
  const float* w4  = (const float*)d_in[15];
  const float* b4  = (const float*)d_in[16];
  float* out = (float*)d_out;
  float* ws  = (float*)d_ws;

  // k_fps uses static LDS. k_grp dynamic (>64KB opt-in).
  size_t dyn_grp = (size_t)GRP_LDS_FLOATS * sizeof(float);  // ~151.6 KB
  hipFuncSetAttribute(reinterpret_cast<const void*>(k_grp),
                      hipFuncAttributeMaxDynamicSharedMemorySize, (int)dyn_grp);

  // invalidate k_fps sync slots (tag field 0xAAAA != any round); graph-safe.
  hipMemsetAsync(ws + WS_SYNC, 0xAA, (size_t)2 * 16 * SB * 8, stream);

  hipLaunchKernelGGL(k_fps, dim3(BB * SB), dim3(NT1), 0, stream,
                     points, out, ws);
  hipLaunchKernelGGL(k_grp, dim3(32), dim3(NT1), dyn_grp, stream,
                     points, ws, w1, b1, g1, be1, m1, v1, w2, b2);
  hipLaunchKernelGGL(k_encB, dim3(512), dim3(256), 0, stream,
                     ws, w3, b3, g2, be2, m2, v2);
  hipLaunchKernelGGL(k_encCb, dim3(768), dim3(256), 0, stream, ws, w4, b4, out);
}